// Round 3
// baseline (148.741 us; speedup 1.0000x reference)
//
#include <hip/hip_runtime.h>

// out[b,h] = (X X^T) X == X (X^T X) per head; X = x[b,h] : [2048 x 64] fp32.
// Single fused persistent kernel: P1 partial Gram -> grid barrier ->
// P2 fixed-order reduce -> grid barrier -> P3 out = X G.
// One kernel dispatch (+1 tiny memset) replaces 3 dispatches: R1/R2 showed
// dur is dominated by per-dispatch overhead, not kernel work.

#define TDIM 2048
#define DDIM 64
#define NHEADS 32
#define NPAIR 16                       // 128-row chunks per head
#define NBLOCKS (NHEADS * NPAIR)       // 512 blocks, 3/CU capacity => co-resident

#define PART_FLOATS (NHEADS * NPAIR * 4096)   // 2,097,152 floats (8.4 MB)
#define G_FLOATS (NHEADS * 4096)              // 131,072 floats
#define BAR_BYTE_OFF ((size_t)(PART_FLOATS + G_FLOATS) * 4)  // 8,912,896 (256-aligned)

// Async global->LDS DMA, 16 B/lane. LDS dest is wave-uniform base; HW scatters
// lane l to base + l*16. Global src is per-lane.
__device__ __forceinline__ void async_copy16(const float* g, float* l) {
    __builtin_amdgcn_global_load_lds(
        (const __attribute__((address_space(1))) void*)g,
        (__attribute__((address_space(3))) void*)l, 16, 0, 0);
}

// Device-scope grid barrier (Guideline 16): release via agent-scope RMW
// (flushes this XCD's L2), acquire via agent-scope load (invalidates L1/L2).
// cnt/rel zeroed by hipMemsetAsync each call -> deterministic across replays.
__device__ __forceinline__ void grid_barrier(unsigned* cnt, unsigned* rel) {
    __syncthreads();   // block writes drained (vmcnt 0) & visible block-wide
    if (threadIdx.x == 0) {
        unsigned old = __hip_atomic_fetch_add(cnt, 1u, __ATOMIC_ACQ_REL,
                                              __HIP_MEMORY_SCOPE_AGENT);
        if (old == NBLOCKS - 1) {
            __hip_atomic_store(rel, 1u, __ATOMIC_RELEASE,
                               __HIP_MEMORY_SCOPE_AGENT);
        } else {
            while (__hip_atomic_load(rel, __ATOMIC_ACQUIRE,
                                     __HIP_MEMORY_SCOPE_AGENT) == 0u)
                __builtin_amdgcn_s_sleep(8);
        }
    }
    __syncthreads();
}

// acc += tile^T * tile contribution for this thread's 4x4 G-tile.
__device__ __forceinline__ void gram_tile(const float* buf, int i0, int j0,
                                          float acc[4][4]) {
#pragma unroll 8
    for (int t = 0; t < 64; ++t) {
        const float4 av = *reinterpret_cast<const float4*>(&buf[t * 64 + i0]);
        const float4 bv = *reinterpret_cast<const float4*>(&buf[t * 64 + j0]);
        const float aa[4] = {av.x, av.y, av.z, av.w};
        const float bb[4] = {bv.x, bv.y, bv.z, bv.w};
#pragma unroll
        for (int a = 0; a < 4; ++a)
#pragma unroll
            for (int q = 0; q < 4; ++q) acc[a][q] += aa[a] * bb[q];
    }
}

// out-tile = xs(64x64) * Gs(64x64) for this thread's 4 rows x 4 cols.
__device__ __forceinline__ void xg_tile(const float* xsb, const float* Gs,
                                        int r0, int d0, float* oh) {
    float acc[4][4];
#pragma unroll
    for (int a = 0; a < 4; ++a)
#pragma unroll
        for (int q = 0; q < 4; ++q) acc[a][q] = 0.f;

#pragma unroll 4
    for (int i = 0; i < 64; i += 4) {
        float4 g[4], xv[4];
#pragma unroll
        for (int ii = 0; ii < 4; ++ii)
            g[ii] = *reinterpret_cast<const float4*>(&Gs[(i + ii) * 64 + d0]);
#pragma unroll
        for (int k = 0; k < 4; ++k)
            xv[k] = *reinterpret_cast<const float4*>(&xsb[(r0 + k) * 64 + i]);
#pragma unroll
        for (int k = 0; k < 4; ++k) {
            const float xk[4] = {xv[k].x, xv[k].y, xv[k].z, xv[k].w};
#pragma unroll
            for (int ii = 0; ii < 4; ++ii) {
                acc[k][0] += xk[ii] * g[ii].x;
                acc[k][1] += xk[ii] * g[ii].y;
                acc[k][2] += xk[ii] * g[ii].z;
                acc[k][3] += xk[ii] * g[ii].w;
            }
        }
    }
#pragma unroll
    for (int k = 0; k < 4; ++k)
        *reinterpret_cast<float4*>(oh + (size_t)(r0 + k) * DDIM + d0) =
            make_float4(acc[k][0], acc[k][1], acc[k][2], acc[k][3]);
}

__global__ __launch_bounds__(256, 4) void fused_attn(const float* __restrict__ x,
                                                     float* __restrict__ out,
                                                     float* __restrict__ ws) {
    __shared__ float smem[12288];   // 48 KB: bufA, bufB, Gs (4096 floats each)
    float* part = ws;
    float* G    = ws + PART_FLOATS;
    unsigned* bar = (unsigned*)((char*)ws + BAR_BYTE_OFF);

    const int b    = blockIdx.x;
    const int tid  = threadIdx.x;
    const int lane = tid & 63;
    const int wv   = tid >> 6;
    const int head = b >> 4;
    const int pair = b & 15;

    const float* xh = x + ((size_t)head * TDIM + pair * 128) * DDIM;
    float* bufA = smem;
    float* bufB = smem + 4096;

    // ---------------- P1: partial Gram over this block's 128 rows ----------
    {
        const float* g0 = xh + wv * 1024 + lane * 4;
#pragma unroll
        for (int it = 0; it < 4; ++it)
            async_copy16(g0 + it * 256, bufA + wv * 1024 + it * 256);
    }
    __syncthreads();   // bufA ready (compiler drains vmcnt before barrier)
    {
        const float* g1 = xh + 64 * DDIM + wv * 1024 + lane * 4;
#pragma unroll
        for (int it = 0; it < 4; ++it)
            async_copy16(g1 + it * 256, bufB + wv * 1024 + it * 256);
    }

    const int i0 = (tid >> 4) << 2;
    const int j0 = (tid & 15) << 2;

    float acc[4][4];
#pragma unroll
    for (int a = 0; a < 4; ++a)
#pragma unroll
        for (int q = 0; q < 4; ++q) acc[a][q] = 0.f;

    gram_tile(bufA, i0, j0, acc);   // overlaps with bufB DMA in flight
    __syncthreads();                // bufB ready
    gram_tile(bufB, i0, j0, acc);

    {
        float* p = part + ((size_t)head * NPAIR + pair) * 4096;
#pragma unroll
        for (int a = 0; a < 4; ++a)
            *reinterpret_cast<float4*>(p + (i0 + a) * 64 + j0) =
                make_float4(acc[a][0], acc[a][1], acc[a][2], acc[a][3]);
    }

    grid_barrier(&bar[0], &bar[16]);

    // ---------------- P2: fixed-order reduce -> G (1 float4 / 64 threads) --
    if (tid < 64) {
        const int gid = b * 64 + tid;              // 0..32767
        const int h   = gid >> 10;
        const int e4  = (gid & 1023) << 2;
        const float* pp = part + (size_t)h * NPAIR * 4096 + e4;
        float4 s = make_float4(0.f, 0.f, 0.f, 0.f);
#pragma unroll
        for (int c = 0; c < NPAIR; ++c) {
            const float4 v = *reinterpret_cast<const float4*>(pp + (size_t)c * 4096);
            s.x += v.x; s.y += v.y; s.z += v.z; s.w += v.w;
        }
        *reinterpret_cast<float4*>(G + (size_t)h * 4096 + e4) = s;
    }

    grid_barrier(&bar[32], &bar[48]);

    // ---------------- P3: out = X G over this block's 128 rows -------------
    float* Gs = smem + 8192;
    const float* Gh = G + (size_t)head * 4096;
    {
        const float* gG = Gh + wv * 1024 + lane * 4;
        const float* g0 = xh + wv * 1024 + lane * 4;
#pragma unroll
        for (int it = 0; it < 4; ++it) {
            async_copy16(gG + it * 256, Gs + wv * 1024 + it * 256);
            async_copy16(g0 + it * 256, bufA + wv * 1024 + it * 256);
        }
    }
    __syncthreads();   // Gs + bufA ready
    {
        const float* g1 = xh + 64 * DDIM + wv * 1024 + lane * 4;
#pragma unroll
        for (int it = 0; it < 4; ++it)
            async_copy16(g1 + it * 256, bufB + wv * 1024 + it * 256);
    }

    const int r0 = (tid >> 4) << 2;
    const int d0 = (tid & 15) << 2;
    float* oh = out + ((size_t)head * TDIM + pair * 128) * DDIM;

    xg_tile(bufA, Gs, r0, d0, oh);          // overlaps bufB DMA
    __syncthreads();                        // bufB ready
    xg_tile(bufB, Gs, r0, d0, oh + 64 * DDIM);
}

extern "C" void kernel_launch(void* const* d_in, const int* in_sizes, int n_in,
                              void* d_out, int out_size, void* d_ws, size_t ws_size,
                              hipStream_t stream) {
    const float* x = (const float*)d_in[0];
    float* out = (float*)d_out;
    float* ws  = (float*)d_ws;

    // Zero the barrier words (256 B) every call -> deterministic replays.
    hipMemsetAsync((char*)d_ws + BAR_BYTE_OFF, 0, 256, stream);

    fused_attn<<<NBLOCKS, 256, 0, stream>>>(x, out, ws);
}

// Round 4
// 46.240 us; speedup vs baseline: 3.2167x; 3.2167x over previous
//
#include <hip/hip_runtime.h>

// out[b,h] = (X X^T) X == X (X^T X) per head; X = x[b,h] : [2048 x 64] fp32.
// ONE dispatch. Per-head producer/consumer sync (no global barrier):
//   - 16 blocks per head each compute a 128-row partial Gram into ws (P1),
//   - last arriver (relaxed agent fetch_add) reduces 16 partials -> G, sets flag,
//   - all 16 blocks poll the flag (relaxed agent loads; NO acquire/release ->
//     no per-poll L2 invalidate storms, the R3 failure mode), then out = X G.
// X rows stay in LDS from P1 to P3 (read from HBM exactly once).
// Deadlock-free without co-residency: counters/flags are monotonic per replay.

#define TDIM 2048
#define DDIM 64
#define NHEADS 32
#define NPAIR 16
#define NBLOCKS (NHEADS * NPAIR)          // 512

#define PART_FLOATS (NBLOCKS * 4096)      // 8.4 MB
#define G_FLOATS (NHEADS * 4096)
#define SYNC_BYTE_OFF ((size_t)(PART_FLOATS + G_FLOATS) * 4)
#define SYNC_BYTES 16384                  // 32 cnt lines + 32 flag lines, 64 u32 apart

// Async global->LDS DMA, 16 B/lane. LDS dest wave-uniform; lane l -> dest + l*16.
__device__ __forceinline__ void async_copy16(const float* g, float* l) {
    __builtin_amdgcn_global_load_lds(
        (const __attribute__((address_space(1))) void*)g,
        (__attribute__((address_space(3))) void*)l, 16, 0, 0);
}

__device__ __forceinline__ float ld_dev(const float* p) {
    return __hip_atomic_load(p, __ATOMIC_RELAXED, __HIP_MEMORY_SCOPE_AGENT);
}
__device__ __forceinline__ void st_dev(float* p, float v) {
    __hip_atomic_store(p, v, __ATOMIC_RELAXED, __HIP_MEMORY_SCOPE_AGENT);
}

// acc += tile^T tile for this thread's 4x4 G-tile. LDS reads are broadcast-
// heavy: av = 4 unique addrs/wave, bv = 16 unique addrs (2-way, free).
__device__ __forceinline__ void gram_tile(const float* buf, int i0, int j0,
                                          float acc[4][4]) {
#pragma unroll 8
    for (int t = 0; t < 64; ++t) {
        const float4 av = *reinterpret_cast<const float4*>(&buf[t * 64 + i0]);
        const float4 bv = *reinterpret_cast<const float4*>(&buf[t * 64 + j0]);
        const float aa[4] = {av.x, av.y, av.z, av.w};
        const float bb[4] = {bv.x, bv.y, bv.z, bv.w};
#pragma unroll
        for (int a = 0; a < 4; ++a)
#pragma unroll
            for (int q = 0; q < 4; ++q) acc[a][q] += aa[a] * bb[q];
    }
}

__device__ __forceinline__ void xg_tile(const float* xsb, const float* Gs,
                                        int r0, int d0, float* oh) {
    float acc[4][4];
#pragma unroll
    for (int a = 0; a < 4; ++a)
#pragma unroll
        for (int q = 0; q < 4; ++q) acc[a][q] = 0.f;

#pragma unroll 4
    for (int i = 0; i < 64; i += 4) {
        float4 g[4], xv[4];
#pragma unroll
        for (int ii = 0; ii < 4; ++ii)
            g[ii] = *reinterpret_cast<const float4*>(&Gs[(i + ii) * 64 + d0]);
#pragma unroll
        for (int k = 0; k < 4; ++k)
            xv[k] = *reinterpret_cast<const float4*>(&xsb[(r0 + k) * 64 + i]);
#pragma unroll
        for (int k = 0; k < 4; ++k) {
            const float xk[4] = {xv[k].x, xv[k].y, xv[k].z, xv[k].w};
#pragma unroll
            for (int ii = 0; ii < 4; ++ii) {
                acc[k][0] += xk[ii] * g[ii].x;
                acc[k][1] += xk[ii] * g[ii].y;
                acc[k][2] += xk[ii] * g[ii].z;
                acc[k][3] += xk[ii] * g[ii].w;
            }
        }
    }
#pragma unroll
    for (int k = 0; k < 4; ++k)
        *reinterpret_cast<float4*>(oh + (size_t)(r0 + k) * DDIM + d0) =
            make_float4(acc[k][0], acc[k][1], acc[k][2], acc[k][3]);
}

__global__ __launch_bounds__(256) void fused_attn(const float* __restrict__ x,
                                                  float* __restrict__ out,
                                                  float* __restrict__ ws) {
    __shared__ float bufA[4096];
    __shared__ float bufB[4096];
    __shared__ float Gs[4096];
    __shared__ int is_red;

    float* part = ws;
    float* G    = ws + PART_FLOATS;
    unsigned* syncw = (unsigned*)((char*)ws + SYNC_BYTE_OFF);

    const int b    = blockIdx.x;
    const int tid  = threadIdx.x;
    const int lane = tid & 63;
    const int wv   = tid >> 6;
    const int head = b >> 4;
    const int pair = b & 15;

    unsigned* cnt = syncw + head * 64;          // one 256 B line per head
    unsigned* flg = syncw + 2048 + head * 64;

    const float* xh = x + ((size_t)head * TDIM + pair * 128) * DDIM;

    // ---- stage this block's 128 rows (two 64x64 tiles) via DMA ----
    {
        const float* g0 = xh + wv * 1024 + lane * 4;
        const float* g1 = g0 + 64 * DDIM;
#pragma unroll
        for (int it = 0; it < 4; ++it) {
            async_copy16(g0 + it * 256, bufA + wv * 1024 + it * 256);
            async_copy16(g1 + it * 256, bufB + wv * 1024 + it * 256);
        }
    }
    __syncthreads();   // compiler drains vmcnt before s_barrier

    // ---- P1: partial Gram over 128 rows ----
    const int i0 = (tid >> 4) << 2;
    const int j0 = (tid & 15) << 2;
    float acc[4][4];
#pragma unroll
    for (int a = 0; a < 4; ++a)
#pragma unroll
        for (int q = 0; q < 4; ++q) acc[a][q] = 0.f;
    gram_tile(bufA, i0, j0, acc);
    gram_tile(bufB, i0, j0, acc);

    {   // device-coherent partial store (relaxed agent: no cache-maint ops)
        float* p = part + (size_t)b * 4096;
#pragma unroll
        for (int a = 0; a < 4; ++a)
#pragma unroll
            for (int q = 0; q < 4; ++q)
                st_dev(p + (i0 + a) * 64 + j0 + q, acc[a][q]);
    }
    asm volatile("s_waitcnt vmcnt(0)" ::: "memory");  // partials at coherent point
    __syncthreads();

    // ---- arrival; 16th arriver for this head reduces ----
    if (tid == 0) {
        unsigned old = __hip_atomic_fetch_add(cnt, 1u, __ATOMIC_RELAXED,
                                              __HIP_MEMORY_SCOPE_AGENT);
        is_red = (old == NPAIR - 1);
    }
    __syncthreads();

    if (is_red) {
        const float* ph = part + (size_t)head * NPAIR * 4096;
        float* gh = G + (size_t)head * 4096;
#pragma unroll
        for (int k = 0; k < 16; ++k) {
            const int e = k * 256 + tid;
            float s = 0.f;
#pragma unroll
            for (int c = 0; c < NPAIR; ++c)
                s += ld_dev(ph + (size_t)c * 4096 + e);   // fixed order: deterministic
            st_dev(gh + e, s);
        }
        asm volatile("s_waitcnt vmcnt(0)" ::: "memory");  // G at coherent point
        __syncthreads();
        if (tid == 0)
            __hip_atomic_store(flg, 1u, __ATOMIC_RELAXED,
                               __HIP_MEMORY_SCOPE_AGENT);
    }

    // ---- wait for this head's G (relaxed polling; flag monotonic per replay) ----
    if (tid == 0) {
        while (__hip_atomic_load(flg, __ATOMIC_RELAXED,
                                 __HIP_MEMORY_SCOPE_AGENT) == 0u)
            __builtin_amdgcn_s_sleep(1);
    }
    __syncthreads();

    // ---- load G into LDS (device-coherent scalar loads, coalesced) ----
    {
        const float* gh = G + (size_t)head * 4096;
#pragma unroll
        for (int k = 0; k < 16; ++k) {
            const int e = k * 256 + tid;
            Gs[e] = ld_dev(gh + e);
        }
    }
    __syncthreads();

    // ---- P3: out = X G (X rows still in bufA/bufB) ----
    const int r0 = (tid >> 4) << 2;
    const int d0 = (tid & 15) << 2;
    float* oh = out + ((size_t)head * TDIM + pair * 128) * DDIM;
    xg_tile(bufA, Gs, r0, d0, oh);
    xg_tile(bufB, Gs, r0, d0, oh + 64 * DDIM);
}

extern "C" void kernel_launch(void* const* d_in, const int* in_sizes, int n_in,
                              void* d_out, int out_size, void* d_ws, size_t ws_size,
                              hipStream_t stream) {
    const float* x = (const float*)d_in[0];
    float* out = (float*)d_out;
    float* ws  = (float*)d_ws;

    // Zero counters/flags every call -> deterministic across graph replays.
    hipMemsetAsync((char*)d_ws + SYNC_BYTE_OFF, 0, SYNC_BYTES, stream);

    fused_attn<<<NBLOCKS, 256, 0, stream>>>(x, out, ws);
}

// Round 6
// 35.008 us; speedup vs baseline: 4.2488x; 1.3209x over previous
//
#include <hip/hip_runtime.h>

// out[b,h] = (X X^T) X == X (X^T X) per head; X = x[b,h] : [2048 x 64] fp32.
// ONE dispatch, per-head producer/consumer sync, all cross-block data via
// coalesced 16B coherent (sc0 sc1) accesses; distributed per-head reduce.
// R5 fix: ext_vector_type(4) for 128-bit inline-asm operands (HIP float4 is a
// struct -> "v" constraint rejects it).

#define TDIM 2048
#define DDIM 64
#define NHEADS 32
#define NPAIR 16
#define NBLOCKS (NHEADS * NPAIR)          // 512

#define PART_FLOATS (NBLOCKS * 4096)      // 8.4 MB
#define G_FLOATS (NHEADS * 4096)
#define SYNC_BYTE_OFF ((size_t)(PART_FLOATS + G_FLOATS) * 4)
#define SYNC_BYTES 16384

typedef float f4 __attribute__((ext_vector_type(4)));

// Async global->LDS DMA, 16 B/lane (normal cached path: read-only input x).
__device__ __forceinline__ void async_copy16(const float* g, float* l) {
    __builtin_amdgcn_global_load_lds(
        (const __attribute__((address_space(1))) void*)g,
        (__attribute__((address_space(3))) void*)l, 16, 0, 0);
}

// Coherent (bypass L1/L2 to the device coherent point) stores/loads.
__device__ __forceinline__ void st16_cc(float* p, f4 v) {
    asm volatile("global_store_dwordx4 %0, %1, off sc0 sc1"
                 :: "v"(p), "v"(v) : "memory");
}
__device__ __forceinline__ void st4_cc(float* p, float v) {
    asm volatile("global_store_dword %0, %1, off sc0 sc1"
                 :: "v"(p), "v"(v) : "memory");
}
__device__ __forceinline__ void wait_vm0() {
    asm volatile("s_waitcnt vmcnt(0)" ::: "memory");
}
// 8 coherent scalar loads issued together, one wait (pipelined latency).
__device__ __forceinline__ void ld8_cc(const float* p0, const float* p1,
                                       const float* p2, const float* p3,
                                       const float* p4, const float* p5,
                                       const float* p6, const float* p7,
                                       float& f0, float& f1, float& f2, float& f3,
                                       float& f4_, float& f5, float& f6, float& f7) {
    asm volatile(
        "global_load_dword %0, %8, off sc0 sc1\n\t"
        "global_load_dword %1, %9, off sc0 sc1\n\t"
        "global_load_dword %2, %10, off sc0 sc1\n\t"
        "global_load_dword %3, %11, off sc0 sc1\n\t"
        "global_load_dword %4, %12, off sc0 sc1\n\t"
        "global_load_dword %5, %13, off sc0 sc1\n\t"
        "global_load_dword %6, %14, off sc0 sc1\n\t"
        "global_load_dword %7, %15, off sc0 sc1\n\t"
        "s_waitcnt vmcnt(0)"
        : "=&v"(f0), "=&v"(f1), "=&v"(f2), "=&v"(f3),
          "=&v"(f4_), "=&v"(f5), "=&v"(f6), "=&v"(f7)
        : "v"(p0), "v"(p1), "v"(p2), "v"(p3),
          "v"(p4), "v"(p5), "v"(p6), "v"(p7)
        : "memory");
}
// 64 B coherent load (4x dwordx4 off one base, imm offsets), one wait.
__device__ __forceinline__ void ld64_cc(const float* p,
                                        f4& v0, f4& v1, f4& v2, f4& v3) {
    asm volatile(
        "global_load_dwordx4 %0, %4, off sc0 sc1\n\t"
        "global_load_dwordx4 %1, %4, off offset:16 sc0 sc1\n\t"
        "global_load_dwordx4 %2, %4, off offset:32 sc0 sc1\n\t"
        "global_load_dwordx4 %3, %4, off offset:48 sc0 sc1\n\t"
        "s_waitcnt vmcnt(0)"
        : "=&v"(v0), "=&v"(v1), "=&v"(v2), "=&v"(v3)
        : "v"(p) : "memory");
}

__device__ __forceinline__ void gram_tile(const float* buf, int i0, int j0,
                                          float acc[4][4]) {
#pragma unroll 8
    for (int t = 0; t < 64; ++t) {
        const float4 av = *reinterpret_cast<const float4*>(&buf[t * 64 + i0]);
        const float4 bv = *reinterpret_cast<const float4*>(&buf[t * 64 + j0]);
        const float aa[4] = {av.x, av.y, av.z, av.w};
        const float bb[4] = {bv.x, bv.y, bv.z, bv.w};
#pragma unroll
        for (int a = 0; a < 4; ++a)
#pragma unroll
            for (int q = 0; q < 4; ++q) acc[a][q] += aa[a] * bb[q];
    }
}

__device__ __forceinline__ void xg_tile(const float* xsb, const float* Gs,
                                        int r0, int d0, float* oh) {
    float acc[4][4];
#pragma unroll
    for (int a = 0; a < 4; ++a)
#pragma unroll
        for (int q = 0; q < 4; ++q) acc[a][q] = 0.f;
#pragma unroll 4
    for (int i = 0; i < 64; i += 4) {
        float4 g[4], xv[4];
#pragma unroll
        for (int ii = 0; ii < 4; ++ii)
            g[ii] = *reinterpret_cast<const float4*>(&Gs[(i + ii) * 64 + d0]);
#pragma unroll
        for (int k = 0; k < 4; ++k)
            xv[k] = *reinterpret_cast<const float4*>(&xsb[(r0 + k) * 64 + i]);
#pragma unroll
        for (int k = 0; k < 4; ++k) {
            const float xk[4] = {xv[k].x, xv[k].y, xv[k].z, xv[k].w};
#pragma unroll
            for (int ii = 0; ii < 4; ++ii) {
                acc[k][0] += xk[ii] * g[ii].x;
                acc[k][1] += xk[ii] * g[ii].y;
                acc[k][2] += xk[ii] * g[ii].z;
                acc[k][3] += xk[ii] * g[ii].w;
            }
        }
    }
#pragma unroll
    for (int k = 0; k < 4; ++k)
        *reinterpret_cast<float4*>(oh + (size_t)(r0 + k) * DDIM + d0) =
            make_float4(acc[k][0], acc[k][1], acc[k][2], acc[k][3]);
}

__global__ __launch_bounds__(256) void fused_attn(const float* __restrict__ x,
                                                  float* __restrict__ out,
                                                  float* __restrict__ ws) {
    __shared__ float bufA[4096];
    __shared__ float bufB[4096];
    __shared__ float Gs[4096];

    float* part = ws;
    float* G    = ws + PART_FLOATS;
    unsigned* syncw = (unsigned*)((char*)ws + SYNC_BYTE_OFF);

    const int b    = blockIdx.x;
    const int tid  = threadIdx.x;
    const int lane = tid & 63;
    const int wv   = tid >> 6;
    const int head = b >> 4;
    const int pair = b & 15;

    unsigned* cnt1 = syncw + head * 64;          // 256 B apart per head
    unsigned* cnt2 = syncw + 2048 + head * 64;

    const float* xh = x + ((size_t)head * TDIM + pair * 128) * DDIM;

    // ---- stage this block's 128 rows via DMA ----
    {
        const float* g0 = xh + wv * 1024 + lane * 4;
        const float* g1 = g0 + 64 * DDIM;
#pragma unroll
        for (int it = 0; it < 4; ++it) {
            async_copy16(g0 + it * 256, bufA + wv * 1024 + it * 256);
            async_copy16(g1 + it * 256, bufB + wv * 1024 + it * 256);
        }
    }
    __syncthreads();

    // ---- P1: partial Gram over 128 rows ----
    const int i0 = (tid >> 4) << 2;
    const int j0 = (tid & 15) << 2;
    float acc[4][4];
#pragma unroll
    for (int a = 0; a < 4; ++a)
#pragma unroll
        for (int q = 0; q < 4; ++q) acc[a][q] = 0.f;
    gram_tile(bufA, i0, j0, acc);
    gram_tile(bufB, i0, j0, acc);

    // Plane layout: part[b][a][tid*4+q]; each store wave-contiguous (1 KB).
    {
        float* p = part + (size_t)b * 4096 + tid * 4;
        st16_cc(p,        f4{acc[0][0], acc[0][1], acc[0][2], acc[0][3]});
        st16_cc(p + 1024, f4{acc[1][0], acc[1][1], acc[1][2], acc[1][3]});
        st16_cc(p + 2048, f4{acc[2][0], acc[2][1], acc[2][2], acc[2][3]});
        st16_cc(p + 3072, f4{acc[3][0], acc[3][1], acc[3][2], acc[3][3]});
    }
    wait_vm0();           // every thread drains its own coherent stores
    __syncthreads();
    if (tid == 0) {
        __hip_atomic_fetch_add(cnt1, 1u, __ATOMIC_RELAXED, __HIP_MEMORY_SCOPE_AGENT);
        while (__hip_atomic_load(cnt1, __ATOMIC_RELAXED, __HIP_MEMORY_SCOPE_AGENT) < NPAIR)
            __builtin_amdgcn_s_sleep(1);
    }
    __syncthreads();

    // ---- distributed reduce: this block sums G-elements [pair*256+tid] ----
    {
        const float* ph = part + (size_t)head * NPAIR * 4096 + pair * 256 + tid;
        float f[16];
        ld8_cc(ph,             ph + 4096,      ph + 2 * 4096,  ph + 3 * 4096,
               ph + 4 * 4096,  ph + 5 * 4096,  ph + 6 * 4096,  ph + 7 * 4096,
               f[0], f[1], f[2], f[3], f[4], f[5], f[6], f[7]);
        ld8_cc(ph + 8 * 4096,  ph + 9 * 4096,  ph + 10 * 4096, ph + 11 * 4096,
               ph + 12 * 4096, ph + 13 * 4096, ph + 14 * 4096, ph + 15 * 4096,
               f[8], f[9], f[10], f[11], f[12], f[13], f[14], f[15]);
        float s = 0.f;
#pragma unroll
        for (int c = 0; c < 16; ++c) s += f[c];   // fixed order: deterministic
        // de-swizzle plane index -> (i,j), store G row-major
        const int a = pair >> 2;
        const int t = ((pair & 3) << 6) + (tid >> 2);
        const int q = tid & 3;
        const int i = 4 * (t >> 4) + a;
        const int j = 4 * (t & 15) + q;
        st4_cc(G + (size_t)head * 4096 + i * 64 + j, s);
    }
    wait_vm0();
    __syncthreads();
    if (tid == 0) {
        __hip_atomic_fetch_add(cnt2, 1u, __ATOMIC_RELAXED, __HIP_MEMORY_SCOPE_AGENT);
        while (__hip_atomic_load(cnt2, __ATOMIC_RELAXED, __HIP_MEMORY_SCOPE_AGENT) < NPAIR)
            __builtin_amdgcn_s_sleep(1);
    }
    __syncthreads();

    // ---- load G (row-major, coherent, coalesced) into LDS ----
    {
        const float* gh = G + (size_t)head * 4096 + tid * 16;
        f4 v0, v1, v2, v3;
        ld64_cc(gh, v0, v1, v2, v3);
        f4* gd = reinterpret_cast<f4*>(&Gs[tid * 16]);
        gd[0] = v0; gd[1] = v1; gd[2] = v2; gd[3] = v3;
    }
    __syncthreads();

    // ---- P3: out = X G (X rows still resident in bufA/bufB) ----
    const int r0 = (tid >> 4) << 2;
    const int d0 = (tid & 15) << 2;
    float* oh = out + ((size_t)head * TDIM + pair * 128) * DDIM;
    xg_tile(bufA, Gs, r0, d0, oh);
    xg_tile(bufB, Gs, r0, d0, oh + 64 * DDIM);
}

extern "C" void kernel_launch(void* const* d_in, const int* in_sizes, int n_in,
                              void* d_out, int out_size, void* d_ws, size_t ws_size,
                              hipStream_t stream) {
    const float* x = (const float*)d_in[0];
    float* out = (float*)d_out;
    float* ws  = (float*)d_ws;

    (void)hipMemsetAsync((char*)d_ws + SYNC_BYTE_OFF, 0, SYNC_BYTES, stream);
    fused_attn<<<NBLOCKS, 256, 0, stream>>>(x, out, ws);
}

// Round 7
// 32.613 us; speedup vs baseline: 4.5608x; 1.0734x over previous
//
#include <hip/hip_runtime.h>

// out[b,h] = (X X^T) X == X (X^T X) per head; X = x[b,h] : [2048 x 64] fp32.
// Two dispatches:
//  K1: DMA-stage 128 rows -> partial Gram -> PLAIN cached partial stores
//      (kernel-end writeback publishes them; no coherent ops, no sync).
//      pair==0 blocks zero their head's counter (no memset node needed).
//  K2: DMA-stage 128 x-rows (overlaps reduce) + reduce 1/16 G-slice from
//      partials (plain cached loads; visible across the kernel boundary),
//      coherent G-slice store -> ONE per-head counter sync -> coherent G
//      gather -> P3 -> out.

#define TDIM 2048
#define DDIM 64
#define NHEADS 32
#define NPAIR 16
#define NBLOCKS (NHEADS * NPAIR)          // 512

#define PART_FLOATS (NBLOCKS * 4096)      // 8.4 MB
#define G_FLOATS (NHEADS * 4096)
#define SYNC_BYTE_OFF ((size_t)(PART_FLOATS + G_FLOATS) * 4)

typedef float f4 __attribute__((ext_vector_type(4)));

// Async global->LDS DMA, 16 B/lane (cached path; read-only x).
__device__ __forceinline__ void async_copy16(const float* g, float* l) {
    __builtin_amdgcn_global_load_lds(
        (const __attribute__((address_space(1))) void*)g,
        (__attribute__((address_space(3))) void*)l, 16, 0, 0);
}

// Coherent-point (sc0 sc1) accesses for the intra-K2 G exchange.
__device__ __forceinline__ void st4_cc(float* p, float v) {
    asm volatile("global_store_dword %0, %1, off sc0 sc1"
                 :: "v"(p), "v"(v) : "memory");
}
__device__ __forceinline__ void wait_vm0() {
    asm volatile("s_waitcnt vmcnt(0)" ::: "memory");
}
__device__ __forceinline__ void ld64_cc(const float* p,
                                        f4& v0, f4& v1, f4& v2, f4& v3) {
    asm volatile(
        "global_load_dwordx4 %0, %4, off sc0 sc1\n\t"
        "global_load_dwordx4 %1, %4, off offset:16 sc0 sc1\n\t"
        "global_load_dwordx4 %2, %4, off offset:32 sc0 sc1\n\t"
        "global_load_dwordx4 %3, %4, off offset:48 sc0 sc1\n\t"
        "s_waitcnt vmcnt(0)"
        : "=&v"(v0), "=&v"(v1), "=&v"(v2), "=&v"(v3)
        : "v"(p) : "memory");
}

__device__ __forceinline__ void gram_tile(const float* buf, int i0, int j0,
                                          float acc[4][4]) {
#pragma unroll 8
    for (int t = 0; t < 64; ++t) {
        const float4 av = *reinterpret_cast<const float4*>(&buf[t * 64 + i0]);
        const float4 bv = *reinterpret_cast<const float4*>(&buf[t * 64 + j0]);
        const float aa[4] = {av.x, av.y, av.z, av.w};
        const float bb[4] = {bv.x, bv.y, bv.z, bv.w};
#pragma unroll
        for (int a = 0; a < 4; ++a)
#pragma unroll
            for (int q = 0; q < 4; ++q) acc[a][q] += aa[a] * bb[q];
    }
}

__device__ __forceinline__ void xg_tile(const float* xsb, const float* Gs,
                                        int r0, int d0, float* oh) {
    float acc[4][4];
#pragma unroll
    for (int a = 0; a < 4; ++a)
#pragma unroll
        for (int q = 0; q < 4; ++q) acc[a][q] = 0.f;
#pragma unroll 4
    for (int i = 0; i < 64; i += 4) {
        float4 g[4], xv[4];
#pragma unroll
        for (int ii = 0; ii < 4; ++ii)
            g[ii] = *reinterpret_cast<const float4*>(&Gs[(i + ii) * 64 + d0]);
#pragma unroll
        for (int k = 0; k < 4; ++k)
            xv[k] = *reinterpret_cast<const float4*>(&xsb[(r0 + k) * 64 + i]);
#pragma unroll
        for (int k = 0; k < 4; ++k) {
            const float xk[4] = {xv[k].x, xv[k].y, xv[k].z, xv[k].w};
#pragma unroll
            for (int ii = 0; ii < 4; ++ii) {
                acc[k][0] += xk[ii] * g[ii].x;
                acc[k][1] += xk[ii] * g[ii].y;
                acc[k][2] += xk[ii] * g[ii].z;
                acc[k][3] += xk[ii] * g[ii].w;
            }
        }
    }
#pragma unroll
    for (int k = 0; k < 4; ++k)
        *reinterpret_cast<float4*>(oh + (size_t)(r0 + k) * DDIM + d0) =
            make_float4(acc[k][0], acc[k][1], acc[k][2], acc[k][3]);
}

// ---------------- K1: partial Gram, all-cached ----------------
__global__ __launch_bounds__(256) void k1_gram(const float* __restrict__ x,
                                               float* __restrict__ ws) {
    __shared__ float bufA[4096];
    __shared__ float bufB[4096];

    float* part = ws;
    unsigned* syncw = (unsigned*)((char*)ws + SYNC_BYTE_OFF);

    const int b    = blockIdx.x;
    const int tid  = threadIdx.x;
    const int lane = tid & 63;
    const int wv   = tid >> 6;
    const int head = b >> 4;
    const int pair = b & 15;

    // Zero this head's counter for K2 (one writer, published at kernel end).
    if (pair == 0 && tid == 0) syncw[head * 64] = 0;

    const float* xh = x + ((size_t)head * TDIM + pair * 128) * DDIM;
    {
        const float* g0 = xh + wv * 1024 + lane * 4;
        const float* g1 = g0 + 64 * DDIM;
#pragma unroll
        for (int it = 0; it < 4; ++it) {
            async_copy16(g0 + it * 256, bufA + wv * 1024 + it * 256);
            async_copy16(g1 + it * 256, bufB + wv * 1024 + it * 256);
        }
    }
    __syncthreads();

    const int i0 = (tid >> 4) << 2;
    const int j0 = (tid & 15) << 2;
    float acc[4][4];
#pragma unroll
    for (int a = 0; a < 4; ++a)
#pragma unroll
        for (int q = 0; q < 4; ++q) acc[a][q] = 0.f;
    gram_tile(bufA, i0, j0, acc);
    gram_tile(bufB, i0, j0, acc);

    // Plane layout part[b][a*1024 + tid*4 + q]; 1 KB contiguous per wave-store.
    float* p = part + (size_t)b * 4096 + tid * 4;
    *reinterpret_cast<f4*>(p)        = f4{acc[0][0], acc[0][1], acc[0][2], acc[0][3]};
    *reinterpret_cast<f4*>(p + 1024) = f4{acc[1][0], acc[1][1], acc[1][2], acc[1][3]};
    *reinterpret_cast<f4*>(p + 2048) = f4{acc[2][0], acc[2][1], acc[2][2], acc[2][3]};
    *reinterpret_cast<f4*>(p + 3072) = f4{acc[3][0], acc[3][1], acc[3][2], acc[3][3]};
}

// ---------------- K2: reduce slice + sync + XG ----------------
__global__ __launch_bounds__(256) void k2_xg(const float* __restrict__ x,
                                             float* __restrict__ out,
                                             float* __restrict__ ws) {
    __shared__ float bufA[4096];
    __shared__ float bufB[4096];
    __shared__ float Gs[4096];

    float* part = ws;
    float* G    = ws + PART_FLOATS;
    unsigned* syncw = (unsigned*)((char*)ws + SYNC_BYTE_OFF);

    const int b    = blockIdx.x;
    const int tid  = threadIdx.x;
    const int lane = tid & 63;
    const int wv   = tid >> 6;
    const int head = b >> 4;
    const int pair = b & 15;

    unsigned* cnt = syncw + head * 64;

    const float* xh = x + ((size_t)head * TDIM + pair * 128) * DDIM;

    // Issue x DMA stage first; it drains under the reduce.
    {
        const float* g0 = xh + wv * 1024 + lane * 4;
        const float* g1 = g0 + 64 * DDIM;
#pragma unroll
        for (int it = 0; it < 4; ++it) {
            async_copy16(g0 + it * 256, bufA + wv * 1024 + it * 256);
            async_copy16(g1 + it * 256, bufB + wv * 1024 + it * 256);
        }
    }

    // Reduce this block's 256-element G slice from 16 partials (plain cached
    // loads -- K1's kernel-end writeback published them; L3-hot).
    {
        const float* ph = part + (size_t)head * NPAIR * 4096 + pair * 256 + tid;
        float f[16];
#pragma unroll
        for (int c = 0; c < 16; ++c) f[c] = ph[(size_t)c * 4096];
        float s = 0.f;
#pragma unroll
        for (int c = 0; c < 16; ++c) s += f[c];   // fixed order: deterministic
        // de-swizzle plane index -> (i,j); store G row-major, coherent.
        const int a = pair >> 2;
        const int t = ((pair & 3) << 6) + (tid >> 2);
        const int q = tid & 3;
        const int i = 4 * (t >> 4) + a;
        const int j = 4 * (t & 15) + q;
        st4_cc(G + (size_t)head * 4096 + i * 64 + j, s);
    }
    wait_vm0();          // G slice at coherent point (also drains DMA + loads)
    __syncthreads();
    if (tid == 0) {
        __hip_atomic_fetch_add(cnt, 1u, __ATOMIC_RELAXED, __HIP_MEMORY_SCOPE_AGENT);
        while (__hip_atomic_load(cnt, __ATOMIC_RELAXED, __HIP_MEMORY_SCOPE_AGENT) < NPAIR)
            __builtin_amdgcn_s_sleep(1);
    }
    __syncthreads();

    // Gather full G (coherent, coalesced 64 B/thread) into LDS.
    {
        const float* gh = G + (size_t)head * 4096 + tid * 16;
        f4 v0, v1, v2, v3;
        ld64_cc(gh, v0, v1, v2, v3);
        f4* gd = reinterpret_cast<f4*>(&Gs[tid * 16]);
        gd[0] = v0; gd[1] = v1; gd[2] = v2; gd[3] = v3;
    }
    __syncthreads();

    // P3: out = X G (x rows resident in bufA/bufB since the DMA).
    const int r0 = (tid >> 4) << 2;
    const int d0 = (tid & 15) << 2;
    float* oh = out + ((size_t)head * TDIM + pair * 128) * DDIM;
    xg_tile(bufA, Gs, r0, d0, oh);
    xg_tile(bufB, Gs, r0, d0, oh + 64 * DDIM);
}

extern "C" void kernel_launch(void* const* d_in, const int* in_sizes, int n_in,
                              void* d_out, int out_size, void* d_ws, size_t ws_size,
                              hipStream_t stream) {
    const float* x = (const float*)d_in[0];
    float* out = (float*)d_out;
    float* ws  = (float*)d_ws;

    k1_gram<<<NBLOCKS, 256, 0, stream>>>(x, ws);
    k2_xg<<<NBLOCKS, 256, 0, stream>>>(x, out, ws);
}